// Round 6
// baseline (300.254 us; speedup 1.0000x reference)
//
#include <hip/hip_runtime.h>

// MSDeformAttn: B=2, LQ=LV=11109, D=256, NH=8, HD=32, NL=3, NP=4
// shapes: (92,92),(46,46),(23,23); starts: 0, 8464, 10580
#define LQn   11109
#define MTOT  22218   // B * LQ

typedef __attribute__((ext_vector_type(8))) short short8;
typedef __attribute__((ext_vector_type(4))) float f32x4;

__device__ __forceinline__ unsigned short f2bf(float f) {
  union { float f; unsigned int u; } v; v.f = f;
  unsigned int r = v.u + 0x7fffu + ((v.u >> 16) & 1u);  // RNE
  return (unsigned short)(r >> 16);
}

__device__ __forceinline__ short8 cvt8(float4 a, float4 b) {
  short8 s;
  s[0] = (short)f2bf(a.x); s[1] = (short)f2bf(a.y);
  s[2] = (short)f2bf(a.z); s[3] = (short)f2bf(a.w);
  s[4] = (short)f2bf(b.x); s[5] = (short)f2bf(b.y);
  s[6] = (short)f2bf(b.z); s[7] = (short)f2bf(b.w);
  return s;
}

// bijective XCD chunk swizzle: consecutive logical blocks -> same XCD
__device__ __forceinline__ int xcd_swz(int bid, int nwg) {
  const int xcd = bid & 7, pos = bid >> 3;
  const int q = nwg >> 3, r = nwg & 7;
  return (xcd < r ? xcd * (q + 1) : r * (q + 1) + (xcd - r) * q) + pos;
}

// ---------------- weight prep: transpose to (N x K) bf16, concat biases ----------------
__global__ __launch_bounds__(256) void prep_weights(
    const float* __restrict__ Wval, const float* __restrict__ Woff,
    const float* __restrict__ Wattn, const float* __restrict__ Wout,
    const float* __restrict__ boff, const float* __restrict__ battn,
    unsigned short* __restrict__ Wval_t, unsigned short* __restrict__ Wcat_t,
    unsigned short* __restrict__ Wout_t, float* __restrict__ bcat) {
  int i = blockIdx.x * 256 + threadIdx.x;   // grid = 288 blocks -> i < 73728
  int n = i >> 8, k = i & 255;              // Wt[n][k] = W[k][n]
  if (n < 256) {
    Wval_t[i] = f2bf(Wval[k * 256 + n]);
    Wout_t[i] = f2bf(Wout[k * 256 + n]);
  }
  float src = (n < 192) ? Woff[k * 192 + n] : Wattn[k * 96 + (n - 192)];
  Wcat_t[i] = f2bf(src);
  if (i < 288) bcat[i] = (i < 192) ? boff[i] : battn[i - 192];
}

// ---------------- fused GEMM1+GEMM2: NO LDS, NO BARRIERS ----------------
// grid = 174*9 (1D, XCD-chunk swizzled). lb = strip*9 + cg.
// cg<4 -> value proj (N=256, bf16 head-major out); cg>=4 -> logits (N=288, fp32).
// Each wave owns a 32x64 output tile; A fragments (fp32, cvt in regs) and
// B fragments (bf16 N-major, 128-144KB -> L2-resident) load DIRECTLY from
// global in MFMA fragment layout. Zero barriers -> all loads independent.
__global__ __launch_bounds__(256) void gemm_fused12(
    const float* __restrict__ Aval,           // (M,256) fp32
    const float* __restrict__ Aq,             // (M,256) fp32
    const unsigned short* __restrict__ Bval,  // (256,256) bf16 N-major
    const unsigned short* __restrict__ Bcat,  // (288,256) bf16 N-major
    const float* __restrict__ bval, const float* __restrict__ bcat,
    unsigned short* __restrict__ value16,     // [b][h][pix][32] bf16
    float* __restrict__ logits) {             // (M,288) fp32
  const int lb = xcd_swz(blockIdx.x, gridDim.x);
  const int strip = lb / 9;
  const int cg = lb - strip * 9;
  const bool is2 = cg >= 4;
  const int n0 = (is2 ? cg - 4 : cg) * 64;
  const float* __restrict__ A = is2 ? Aq : Aval;
  const unsigned short* __restrict__ Bt = is2 ? Bcat : Bval;
  const float* __restrict__ bias = is2 ? bcat : bval;
  const int N = is2 ? 288 : 256;

  const int t = threadIdx.x;
  const int wave = t >> 6, lane = t & 63;
  const int quad = lane >> 4, l16 = lane & 15;
  const int m0 = strip * 128 + wave * 32;    // wave's 32 rows

  const int r0 = m0 + l16, r1 = m0 + 16 + l16;
  const bool av0 = r0 < MTOT, av1 = r1 < MTOT;
  const float* ap0 = A + (size_t)r0 * 256 + quad * 8;
  const float* ap1 = A + (size_t)r1 * 256 + quad * 8;

  const unsigned short* bp[4];
  bool bv[4];
#pragma unroll
  for (int nf = 0; nf < 4; nf++) {
    const int col = n0 + nf * 16 + l16;
    bv[nf] = col < N;
    bp[nf] = Bt + (size_t)col * 256 + quad * 8;
  }

  f32x4 acc[2][4];
#pragma unroll
  for (int mf = 0; mf < 2; mf++)
#pragma unroll
    for (int nf = 0; nf < 4; nf++) acc[mf][nf] = (f32x4){0.f, 0.f, 0.f, 0.f};

  const float4 z4 = {0.f, 0.f, 0.f, 0.f};
#pragma unroll 2
  for (int kb = 0; kb < 8; kb++) {
    const int ko = kb * 32;
    float4 x0 = av0 ? *(const float4*)(ap0 + ko) : z4;
    float4 x1 = av0 ? *(const float4*)(ap0 + ko + 4) : z4;
    float4 y0 = av1 ? *(const float4*)(ap1 + ko) : z4;
    float4 y1 = av1 ? *(const float4*)(ap1 + ko + 4) : z4;
    short8 bfr[4];
#pragma unroll
    for (int nf = 0; nf < 4; nf++)
      bfr[nf] = bv[nf] ? *(const short8*)(bp[nf] + ko) : (short8){0,0,0,0,0,0,0,0};
    const short8 a0 = cvt8(x0, x1);
    const short8 a1 = cvt8(y0, y1);
#pragma unroll
    for (int nf = 0; nf < 4; nf++) {
      acc[0][nf] = __builtin_amdgcn_mfma_f32_16x16x32_bf16(a0, bfr[nf], acc[0][nf], 0, 0, 0);
      acc[1][nf] = __builtin_amdgcn_mfma_f32_16x16x32_bf16(a1, bfr[nf], acc[1][nf], 0, 0, 0);
    }
  }

#pragma unroll
  for (int mf = 0; mf < 2; mf++)
#pragma unroll
    for (int nf = 0; nf < 4; nf++) {
      const int colg = n0 + nf * 16 + l16;
      if (colg >= N) continue;
      const float bsv = bias[colg];
      const int row0 = m0 + mf * 16 + quad * 4;
#pragma unroll
      for (int r = 0; r < 4; r++) {
        const int rg = row0 + r;
        if (rg >= MTOT) continue;
        const float v = acc[mf][nf][r] + bsv;
        if (is2) {
          logits[(size_t)rg * 288 + colg] = v;
        } else {
          const int b = (rg >= LQn) ? 1 : 0;
          const int p = rg - b * LQn;
          value16[((size_t)(b * 8 + (colg >> 5)) * LQn + p) * 32 + (colg & 31)] = f2bf(v);
        }
      }
    }
}

// ---------------- GEMM3: NO LDS, NO BARRIERS, A bf16 ----------------
// grid = 348*4 (1D, XCD-chunk swizzled). lb = strip*4 + cg; wave owns 16x64.
__global__ __launch_bounds__(256) void gemm_a16(
    const unsigned short* __restrict__ A,   // (M,256) bf16
    const unsigned short* __restrict__ Bt,  // (256,256) bf16 N-major
    const float* __restrict__ bias,
    float* __restrict__ C) {                // (M,256) fp32
  const int lb = xcd_swz(blockIdx.x, gridDim.x);
  const int strip = lb >> 2;
  const int n0 = (lb & 3) * 64;

  const int t = threadIdx.x;
  const int wave = t >> 6, lane = t & 63;
  const int quad = lane >> 4, l16 = lane & 15;
  const int m0 = strip * 64 + wave * 16;

  const int r0 = m0 + l16;
  const bool av0 = r0 < MTOT;
  const unsigned short* ap = A + (size_t)r0 * 256 + quad * 8;

  const unsigned short* bp[4];
#pragma unroll
  for (int nf = 0; nf < 4; nf++)
    bp[nf] = Bt + (size_t)(n0 + nf * 16 + l16) * 256 + quad * 8;  // col < 256 always

  f32x4 acc[4];
#pragma unroll
  for (int nf = 0; nf < 4; nf++) acc[nf] = (f32x4){0.f, 0.f, 0.f, 0.f};

#pragma unroll 2
  for (int kb = 0; kb < 8; kb++) {
    const int ko = kb * 32;
    const short8 a0 = av0 ? *(const short8*)(ap + ko) : (short8){0,0,0,0,0,0,0,0};
    short8 bfr[4];
#pragma unroll
    for (int nf = 0; nf < 4; nf++) bfr[nf] = *(const short8*)(bp[nf] + ko);
#pragma unroll
    for (int nf = 0; nf < 4; nf++)
      acc[nf] = __builtin_amdgcn_mfma_f32_16x16x32_bf16(a0, bfr[nf], acc[nf], 0, 0, 0);
  }

#pragma unroll
  for (int nf = 0; nf < 4; nf++) {
    const int colg = n0 + nf * 16 + l16;
    const float bsv = bias[colg];
    const int row0 = m0 + quad * 4;
#pragma unroll
    for (int r = 0; r < 4; r++) {
      const int rg = row0 + r;
      if (rg < MTOT) C[(size_t)rg * 256 + colg] = acc[nf][r] + bsv;
    }
  }
}

// ---------------- sampling + softmax + weighted sum, v4 + XCD swizzle ----------------
// Phase C reverted to the simple loop (VGPR 40, occupancy ~47%): manual deep
// pipelining (v6) cost 128 VGPR -> 19% occupancy -> 63 us vs 43 us.
__global__ __launch_bounds__(256) void msda_sample4(
    const unsigned short* __restrict__ value16,  // [b][h][pix][32] bf16
    const float* __restrict__ logits,            // (M,288)
    const float* __restrict__ refp,              // (M,3,2) (y,x)
    unsigned short* __restrict__ sampled) {      // (M,256) bf16
  __shared__ float          tw[8][96][4];   // 12.3 KB
  __shared__ unsigned short ti[8][96][4];   // 6.1 KB
  __shared__ float hmx[8][8], hrd[8][8];
  __shared__ float rfs[8][6];

  const int t = threadIdx.x;
  const int nbid = xcd_swz(blockIdx.x, gridDim.x);
  const int qbase = nbid * 8;

  // refp: 48 consecutive floats
  if (t < 48) {
    int q = t / 6;
    if (qbase + q < MTOT) rfs[q][t - q * 6] = refp[(size_t)qbase * 6 + t];
  }
  // softmax stats: 64 (q,h) tasks, logits read from global (L2-hot)
  if (t >= 64 && t < 128) {
    int tt = t - 64;
    int q = tt >> 3, h = tt & 7;
    int bq = qbase + q;
    if (bq < MTOT) {
      const float* lrow = logits + (size_t)bq * 288 + 192 + h * 12;
      float mx = -1e30f;
#pragma unroll
      for (int i = 0; i < 12; i++) mx = fmaxf(mx, lrow[i]);
      float den = 0.f;
#pragma unroll
      for (int i = 0; i < 12; i++) den += __expf(lrow[i] - mx);
      hmx[q][h] = mx;
      hrd[q][h] = 1.0f / den;
    }
  }
  __syncthreads();

  // build tables: 8q x 96 slots = 768 tasks
  {
    const int Hs[3] = {92, 46, 23};
    const int Ss[3] = {0, 8464, 10580};
#pragma unroll
    for (int r = 0; r < 3; r++) {
      const int task = t + r * 256;
      const int q = task / 96, s = task - q * 96;
      const int bq = qbase + q;
      if (bq < MTOT) {
        const int h = s / 12, pl = s - h * 12;
        const int l = pl >> 2;
        const int H = Hs[l], W = Hs[l], S = Ss[l];
        const float* lrow = logits + (size_t)bq * 288;
        const float aw = __expf(lrow[192 + s] - hmx[q][h]) * hrd[q][h];
        const float offy = lrow[2 * s], offx = lrow[2 * s + 1];
        const float x = rfs[q][l * 2 + 1] * W + offx - 0.5f;
        const float y = rfs[q][l * 2 + 0] * H + offy - 0.5f;
        const float xf = floorf(x), yf = floorf(y);
        const int x0 = (int)xf, y0 = (int)yf;
        const float lx = x - xf, ly = y - yf;
        const bool xv0 = (x0 >= 0) & (x0 < W), xv1 = (x0 + 1 >= 0) & (x0 + 1 < W);
        const bool yv0 = (y0 >= 0) & (y0 < H), yv1 = (y0 + 1 >= 0) & (y0 + 1 < H);
        const int xc0 = min(max(x0, 0), W - 1), xc1 = min(max(x0 + 1, 0), W - 1);
        const int yc0 = min(max(y0, 0), H - 1), yc1 = min(max(y0 + 1, 0), H - 1);
        const int slot = pl * 8 + h;
        ti[q][slot][0] = (unsigned short)(S + yc0 * W + xc0);
        ti[q][slot][1] = (unsigned short)(S + yc0 * W + xc1);
        ti[q][slot][2] = (unsigned short)(S + yc1 * W + xc0);
        ti[q][slot][3] = (unsigned short)(S + yc1 * W + xc1);
        tw[q][slot][0] = (yv0 & xv0) ? aw * (1.f - ly) * (1.f - lx) : 0.f;
        tw[q][slot][1] = (yv0 & xv1) ? aw * (1.f - ly) * lx : 0.f;
        tw[q][slot][2] = (yv1 & xv0) ? aw * ly * (1.f - lx) : 0.f;
        tw[q][slot][3] = (yv1 & xv1) ? aw * ly * lx : 0.f;
      }
    }
  }
  __syncthreads();

  // gather + weighted sum: wave w handles queries qbase + 2w + {0,1}
  {
    const int w = t >> 6, lane = t & 63;
    const int q = w * 2 + (lane >> 5);
    const int h = (lane >> 2) & 7, cg = lane & 3;
    const int bq = qbase + q;
    const bool qv = bq < MTOT;
    const int bqc = qv ? bq : 0;
    const char* __restrict__ vb =
        (const char*)value16 + (size_t)(bqc / LQn) * ((size_t)LQn * 512);
    const unsigned laneoff = (unsigned)h * (LQn * 64u) + (unsigned)cg * 16u;

    float a0 = 0.f, a1 = 0.f, a2 = 0.f, a3 = 0.f;
    float a4 = 0.f, a5 = 0.f, a6 = 0.f, a7 = 0.f;
#pragma unroll
    for (int p = 0; p < 12; p++) {
      const int slot = p * 8 + h;
      const ushort4 tiv = *(const ushort4*)(&ti[q][slot][0]);
      const f32x4 wv = *(const f32x4*)(&tw[q][slot][0]);
#pragma unroll
      for (int k = 0; k < 4; k++) {
        const unsigned pix =
            (k == 0) ? tiv.x : (k == 1) ? tiv.y : (k == 2) ? tiv.z : tiv.w;
        const float wgt = wv[k];
        const uint4 u = *(const uint4*)(vb + ((pix << 6) + laneoff));
        a0 += wgt * __uint_as_float(u.x << 16);
        a1 += wgt * __uint_as_float(u.x & 0xffff0000u);
        a2 += wgt * __uint_as_float(u.y << 16);
        a3 += wgt * __uint_as_float(u.y & 0xffff0000u);
        a4 += wgt * __uint_as_float(u.z << 16);
        a5 += wgt * __uint_as_float(u.z & 0xffff0000u);
        a6 += wgt * __uint_as_float(u.w << 16);
        a7 += wgt * __uint_as_float(u.w & 0xffff0000u);
      }
    }
    if (qv) {
      uint4 o;
      o.x = (unsigned)f2bf(a0) | ((unsigned)f2bf(a1) << 16);
      o.y = (unsigned)f2bf(a2) | ((unsigned)f2bf(a3) << 16);
      o.z = (unsigned)f2bf(a4) | ((unsigned)f2bf(a5) << 16);
      o.w = (unsigned)f2bf(a6) | ((unsigned)f2bf(a7) << 16);
      *(uint4*)(sampled + (size_t)bq * 256 + h * 32 + cg * 8) = o;
    }
  }
}

// ---------------- host launch ----------------
extern "C" void kernel_launch(void* const* d_in, const int* in_sizes, int n_in,
                              void* d_out, int out_size, void* d_ws, size_t ws_size,
                              hipStream_t stream) {
  const float* query      = (const float*)d_in[0];
  const float* refp       = (const float*)d_in[1];
  const float* value_flat = (const float*)d_in[2];
  const float* W_val      = (const float*)d_in[3];
  const float* b_val      = (const float*)d_in[4];
  const float* W_off      = (const float*)d_in[5];
  const float* b_off      = (const float*)d_in[6];
  const float* W_attn     = (const float*)d_in[7];
  const float* b_attn     = (const float*)d_in[8];
  const float* W_out      = (const float*)d_in[9];
  const float* b_out      = (const float*)d_in[10];

  char* w = (char*)d_ws;
  size_t o = 0;
  auto carve = [&](size_t bytes) -> void* {
    void* p = (void*)(w + o);
    o += (bytes + 255) & ~(size_t)255;
    return p;
  };
  unsigned short* Wval_t  = (unsigned short*)carve(256 * 256 * 2);
  unsigned short* Wcat_t  = (unsigned short*)carve(288 * 256 * 2);
  unsigned short* Wout_t  = (unsigned short*)carve(256 * 256 * 2);
  float*          bcat    = (float*)carve(288 * 4);
  unsigned short* value16 = (unsigned short*)carve((size_t)MTOT * 256 * 2);
  float*          logits  = (float*)carve((size_t)MTOT * 288 * 4);
  unsigned short* samp_bf = (unsigned short*)carve((size_t)MTOT * 256 * 2);

  prep_weights<<<288, 256, 0, stream>>>(W_val, W_off, W_attn, W_out, b_off, b_attn,
                                        Wval_t, Wcat_t, Wout_t, bcat);

  const int mg128 = (MTOT + 127) / 128;          // 174
  gemm_fused12<<<mg128 * 9, 256, 0, stream>>>(value_flat, query, Wval_t, Wcat_t,
                                              b_val, bcat, value16, logits);

  const int sgrid = (MTOT + 7) / 8;              // 2778
  msda_sample4<<<sgrid, 256, 0, stream>>>(value16, logits, refp, samp_bf);

  const int mg64 = (MTOT + 63) / 64;             // 348
  gemm_a16<<<mg64 * 4, 256, 0, stream>>>(samp_bf, Wout_t, b_out, (float*)d_out);
}

// Round 7
// 212.046 us; speedup vs baseline: 1.4160x; 1.4160x over previous
//
#include <hip/hip_runtime.h>

// MSDeformAttn: B=2, LQ=LV=11109, D=256, NH=8, HD=32, NL=3, NP=4
// shapes: (92,92),(46,46),(23,23); starts: 0, 8464, 10580
#define LQn   11109
#define MTOT  22218   // B * LQ

typedef __attribute__((ext_vector_type(8))) short short8;
typedef __attribute__((ext_vector_type(4))) float f32x4;

__device__ __forceinline__ unsigned short f2bf(float f) {
  union { float f; unsigned int u; } v; v.f = f;
  unsigned int r = v.u + 0x7fffu + ((v.u >> 16) & 1u);  // RNE
  return (unsigned short)(r >> 16);
}

__device__ __forceinline__ uint4 pack8(const float4 a, const float4 b) {
  uint4 u;
  u.x = (unsigned)f2bf(a.x) | ((unsigned)f2bf(a.y) << 16);
  u.y = (unsigned)f2bf(a.z) | ((unsigned)f2bf(a.w) << 16);
  u.z = (unsigned)f2bf(b.x) | ((unsigned)f2bf(b.y) << 16);
  u.w = (unsigned)f2bf(b.z) | ((unsigned)f2bf(b.w) << 16);
  return u;
}

// bijective XCD chunk swizzle: consecutive logical blocks -> same XCD
__device__ __forceinline__ int xcd_swz(int bid, int nwg) {
  const int xcd = bid & 7, pos = bid >> 3;
  const int q = nwg >> 3, r = nwg & 7;
  return (xcd < r ? xcd * (q + 1) : r * (q + 1) + (xcd - r) * q) + pos;
}

// ---------------- weight prep: transpose to (N x K) bf16, concat biases ----------------
__global__ __launch_bounds__(256) void prep_weights(
    const float* __restrict__ Wval, const float* __restrict__ Woff,
    const float* __restrict__ Wattn, const float* __restrict__ Wout,
    const float* __restrict__ boff, const float* __restrict__ battn,
    unsigned short* __restrict__ Wval_t, unsigned short* __restrict__ Wcat_t,
    unsigned short* __restrict__ Wout_t, float* __restrict__ bcat) {
  int i = blockIdx.x * 256 + threadIdx.x;   // grid = 288 blocks -> i < 73728
  int n = i >> 8, k = i & 255;              // Wt[n][k] = W[k][n]
  if (n < 256) {
    Wval_t[i] = f2bf(Wval[k * 256 + n]);
    Wout_t[i] = f2bf(Wout[k * 256 + n]);
  }
  float src = (n < 192) ? Woff[k * 192 + n] : Wattn[k * 96 + (n - 192)];
  Wcat_t[i] = f2bf(src);
  if (i < 288) bcat[i] = (i < 192) ? boff[i] : battn[i - 192];
}

// ---------------- fused GEMM1+GEMM2 v4: A-LDS once -> A-frags in REGISTERS,
// per-bn B tile staged coalesced into LDS (B is 128-144KB -> L2-hot).
// Barriers: 1 after A stage, then 2 per bn (none coupled to HBM latency).
// grid (348, 2): y=0 -> value proj (N=256, bf16 head-major out)
//                y=1 -> logits proj (N=288, fp32 out)
__global__ __launch_bounds__(256) void gemm_fused12(
    const float* __restrict__ Aval,           // (M,256) fp32
    const float* __restrict__ Aq,             // (M,256) fp32
    const unsigned short* __restrict__ Bval,  // (256,256) bf16 N-major
    const unsigned short* __restrict__ Bcat,  // (288,256) bf16 N-major
    const float* __restrict__ bval, const float* __restrict__ bcat,
    unsigned short* __restrict__ value16,     // [b][h][pix][32] bf16
    float* __restrict__ logits) {             // (M,288) fp32
  __shared__ unsigned short As[64][264];      // 33.8 KB
  __shared__ unsigned short Bs[64][264];      // 33.8 KB

  const bool is2 = blockIdx.y == 1;
  const float* __restrict__ A = is2 ? Aq : Aval;
  const unsigned short* __restrict__ Bt = is2 ? Bcat : Bval;
  const float* __restrict__ bias = is2 ? bcat : bval;
  const int N = is2 ? 288 : 256;
  const int NB = is2 ? 5 : 4;

  const int bm = blockIdx.x;
  const int t = threadIdx.x;
  const int wave = t >> 6, lane = t & 63;
  const int wm = wave >> 1, wn = wave & 1;
  const int quad = lane >> 4, l16 = lane & 15;

  const int ldr = t >> 2;          // 0..63
  const int ldk = (t & 3) * 8;     // fp32 staging offset (floats)
  const int arow = bm * 64 + ldr;

  // ---- stage A panel (fp32 -> bf16), coalesced, once ----
#pragma unroll
  for (int kb = 0; kb < 8; kb++) {
    float4 a0 = {0.f, 0.f, 0.f, 0.f}, a1 = a0;
    if (arow < MTOT) {
      a0 = *(const float4*)(A + (size_t)arow * 256 + kb * 32 + ldk);
      a1 = *(const float4*)(A + (size_t)arow * 256 + kb * 32 + ldk + 4);
    }
    *(uint4*)(&As[ldr][kb * 32 + ldk]) = pack8(a0, a1);
  }
  __syncthreads();

  // ---- hoist this wave's A fragments into registers (As never overwritten) ----
  short8 af[8][2];
#pragma unroll
  for (int kb = 0; kb < 8; kb++) {
    af[kb][0] = *(const short8*)(&As[wm * 32 + l16][kb * 32 + quad * 8]);
    af[kb][1] = *(const short8*)(&As[wm * 32 + 16 + l16][kb * 32 + quad * 8]);
  }

  const int bcol = (t & 3) * 64;   // B staging: 4 threads cover one 256-col row

  for (int bn = 0; bn < NB; bn++) {
    // protect Bs from previous iteration's readers
    __syncthreads();
    {
      const int brg = bn * 64 + ldr;
      const bool ok = brg < N;
#pragma unroll
      for (int u = 0; u < 4; u++) {
        uint4 b0 = {0u, 0u, 0u, 0u};
        if (ok) b0 = *(const uint4*)(Bt + (size_t)brg * 256 + bcol + u * 8);
        *(uint4*)(&Bs[ldr][bcol + u * 8]) = b0;
      }
      // 4 uint4 = 64 ushorts? No: 4*8=32 ushorts... cover remaining 32:
#pragma unroll
      for (int u = 4; u < 8; u++) {
        uint4 b0 = {0u, 0u, 0u, 0u};
        if (ok) b0 = *(const uint4*)(Bt + (size_t)brg * 256 + bcol + u * 8);
        *(uint4*)(&Bs[ldr][bcol + u * 8]) = b0;
      }
    }
    __syncthreads();

    f32x4 acc[2][2];
#pragma unroll
    for (int i = 0; i < 2; i++)
#pragma unroll
      for (int j = 0; j < 2; j++) acc[i][j] = (f32x4){0.f, 0.f, 0.f, 0.f};

#pragma unroll
    for (int kb = 0; kb < 8; kb++) {
      short8 bfr[2];
      bfr[0] = *(const short8*)(&Bs[wn * 32 + l16][kb * 32 + quad * 8]);
      bfr[1] = *(const short8*)(&Bs[wn * 32 + 16 + l16][kb * 32 + quad * 8]);
#pragma unroll
      for (int i = 0; i < 2; i++)
#pragma unroll
        for (int j = 0; j < 2; j++)
          acc[i][j] = __builtin_amdgcn_mfma_f32_16x16x32_bf16(af[kb][i], bfr[j], acc[i][j], 0, 0, 0);
    }

#pragma unroll
    for (int i = 0; i < 2; i++)
#pragma unroll
      for (int j = 0; j < 2; j++) {
        const int colg = bn * 64 + wn * 32 + j * 16 + l16;
        if (colg >= N) continue;
        const float bsv = bias[colg];
        const int row0 = bm * 64 + wm * 32 + i * 16 + quad * 4;
#pragma unroll
        for (int r = 0; r < 4; r++) {
          const int rg = row0 + r;
          if (rg >= MTOT) continue;
          const float v = acc[i][j][r] + bsv;
          if (is2) {
            logits[(size_t)rg * 288 + colg] = v;
          } else {
            const int b = (rg >= LQn) ? 1 : 0;
            const int p = rg - b * LQn;
            value16[((size_t)(b * 8 + (colg >> 5)) * LQn + p) * 32 + (colg & 31)] = f2bf(v);
          }
        }
      }
  }
}

// ---------------- GEMM3 v4: same skeleton, A bf16, out fp32 ----------------
__global__ __launch_bounds__(256) void gemm_a16(
    const unsigned short* __restrict__ A,   // (M,256) bf16
    const unsigned short* __restrict__ Bt,  // (256,256) bf16 N-major
    const float* __restrict__ bias,
    float* __restrict__ C) {                // (M,256) fp32
  __shared__ unsigned short As[64][264];
  __shared__ unsigned short Bs[64][264];

  const int bm = blockIdx.x;
  const int t = threadIdx.x;
  const int wave = t >> 6, lane = t & 63;
  const int wm = wave >> 1, wn = wave & 1;
  const int quad = lane >> 4, l16 = lane & 15;

  const int ldr = t >> 2;
  const int ldk = (t & 3) * 8;     // ushort staging offset
  const int arow = bm * 64 + ldr;

#pragma unroll
  for (int kb = 0; kb < 8; kb++) {
    uint4 av = {0u, 0u, 0u, 0u};
    if (arow < MTOT) av = *(const uint4*)(A + (size_t)arow * 256 + kb * 32 + ldk);
    *(uint4*)(&As[ldr][kb * 32 + ldk]) = av;
  }
  __syncthreads();

  short8 af[8][2];
#pragma unroll
  for (int kb = 0; kb < 8; kb++) {
    af[kb][0] = *(const short8*)(&As[wm * 32 + l16][kb * 32 + quad * 8]);
    af[kb][1] = *(const short8*)(&As[wm * 32 + 16 + l16][kb * 32 + quad * 8]);
  }

  const int bcol = (t & 3) * 64;

  for (int bn = 0; bn < 4; bn++) {
    __syncthreads();
    {
      const int brg = bn * 64 + ldr;   // < 256 always
#pragma unroll
      for (int u = 0; u < 8; u++) {
        uint4 b0 = *(const uint4*)(Bt + (size_t)brg * 256 + bcol + u * 8);
        *(uint4*)(&Bs[ldr][bcol + u * 8]) = b0;
      }
    }
    __syncthreads();

    f32x4 acc[2][2];
#pragma unroll
    for (int i = 0; i < 2; i++)
#pragma unroll
      for (int j = 0; j < 2; j++) acc[i][j] = (f32x4){0.f, 0.f, 0.f, 0.f};

#pragma unroll
    for (int kb = 0; kb < 8; kb++) {
      short8 bfr[2];
      bfr[0] = *(const short8*)(&Bs[wn * 32 + l16][kb * 32 + quad * 8]);
      bfr[1] = *(const short8*)(&Bs[wn * 32 + 16 + l16][kb * 32 + quad * 8]);
#pragma unroll
      for (int i = 0; i < 2; i++)
#pragma unroll
        for (int j = 0; j < 2; j++)
          acc[i][j] = __builtin_amdgcn_mfma_f32_16x16x32_bf16(af[kb][i], bfr[j], acc[i][j], 0, 0, 0);
    }

#pragma unroll
    for (int i = 0; i < 2; i++)
#pragma unroll
      for (int j = 0; j < 2; j++) {
        const int colg = bn * 64 + wn * 32 + j * 16 + l16;
        const float bsv = bias[colg];
        const int row0 = bm * 64 + wm * 32 + i * 16 + quad * 4;
#pragma unroll
        for (int r = 0; r < 4; r++) {
          const int rg = row0 + r;
          if (rg < MTOT) C[(size_t)rg * 256 + colg] = acc[i][j][r] + bsv;
        }
      }
  }
}

// ---------------- sampling + softmax + weighted sum, v4 + XCD swizzle ----------------
// (proven 43 us; VGPR 40, occupancy ~47%)
__global__ __launch_bounds__(256) void msda_sample4(
    const unsigned short* __restrict__ value16,  // [b][h][pix][32] bf16
    const float* __restrict__ logits,            // (M,288)
    const float* __restrict__ refp,              // (M,3,2) (y,x)
    unsigned short* __restrict__ sampled) {      // (M,256) bf16
  __shared__ float          tw[8][96][4];   // 12.3 KB
  __shared__ unsigned short ti[8][96][4];   // 6.1 KB
  __shared__ float hmx[8][8], hrd[8][8];
  __shared__ float rfs[8][6];

  const int t = threadIdx.x;
  const int nbid = xcd_swz(blockIdx.x, gridDim.x);
  const int qbase = nbid * 8;

  if (t < 48) {
    int q = t / 6;
    if (qbase + q < MTOT) rfs[q][t - q * 6] = refp[(size_t)qbase * 6 + t];
  }
  if (t >= 64 && t < 128) {
    int tt = t - 64;
    int q = tt >> 3, h = tt & 7;
    int bq = qbase + q;
    if (bq < MTOT) {
      const float* lrow = logits + (size_t)bq * 288 + 192 + h * 12;
      float mx = -1e30f;
#pragma unroll
      for (int i = 0; i < 12; i++) mx = fmaxf(mx, lrow[i]);
      float den = 0.f;
#pragma unroll
      for (int i = 0; i < 12; i++) den += __expf(lrow[i] - mx);
      hmx[q][h] = mx;
      hrd[q][h] = 1.0f / den;
    }
  }
  __syncthreads();

  {
    const int Hs[3] = {92, 46, 23};
    const int Ss[3] = {0, 8464, 10580};
#pragma unroll
    for (int r = 0; r < 3; r++) {
      const int task = t + r * 256;
      const int q = task / 96, s = task - q * 96;
      const int bq = qbase + q;
      if (bq < MTOT) {
        const int h = s / 12, pl = s - h * 12;
        const int l = pl >> 2;
        const int H = Hs[l], W = Hs[l], S = Ss[l];
        const float* lrow = logits + (size_t)bq * 288;
        const float aw = __expf(lrow[192 + s] - hmx[q][h]) * hrd[q][h];
        const float offy = lrow[2 * s], offx = lrow[2 * s + 1];
        const float x = rfs[q][l * 2 + 1] * W + offx - 0.5f;
        const float y = rfs[q][l * 2 + 0] * H + offy - 0.5f;
        const float xf = floorf(x), yf = floorf(y);
        const int x0 = (int)xf, y0 = (int)yf;
        const float lx = x - xf, ly = y - yf;
        const bool xv0 = (x0 >= 0) & (x0 < W), xv1 = (x0 + 1 >= 0) & (x0 + 1 < W);
        const bool yv0 = (y0 >= 0) & (y0 < H), yv1 = (y0 + 1 >= 0) & (y0 + 1 < H);
        const int xc0 = min(max(x0, 0), W - 1), xc1 = min(max(x0 + 1, 0), W - 1);
        const int yc0 = min(max(y0, 0), H - 1), yc1 = min(max(y0 + 1, 0), H - 1);
        const int slot = pl * 8 + h;
        ti[q][slot][0] = (unsigned short)(S + yc0 * W + xc0);
        ti[q][slot][1] = (unsigned short)(S + yc0 * W + xc1);
        ti[q][slot][2] = (unsigned short)(S + yc1 * W + xc0);
        ti[q][slot][3] = (unsigned short)(S + yc1 * W + xc1);
        tw[q][slot][0] = (yv0 & xv0) ? aw * (1.f - ly) * (1.f - lx) : 0.f;
        tw[q][slot][1] = (yv0 & xv1) ? aw * (1.f - ly) * lx : 0.f;
        tw[q][slot][2] = (yv1 & xv0) ? aw * ly * (1.f - lx) : 0.f;
        tw[q][slot][3] = (yv1 & xv1) ? aw * ly * lx : 0.f;
      }
    }
  }
  __syncthreads();

  {
    const int w = t >> 6, lane = t & 63;
    const int q = w * 2 + (lane >> 5);
    const int h = (lane >> 2) & 7, cg = lane & 3;
    const int bq = qbase + q;
    const bool qv = bq < MTOT;
    const int bqc = qv ? bq : 0;
    const char* __restrict__ vb =
        (const char*)value16 + (size_t)(bqc / LQn) * ((size_t)LQn * 512);
    const unsigned laneoff = (unsigned)h * (LQn * 64u) + (unsigned)cg * 16u;

    float a0 = 0.f, a1 = 0.f, a2 = 0.f, a3 = 0.f;
    float a4 = 0.f, a5 = 0.f, a6 = 0.f, a7 = 0.f;
#pragma unroll
    for (int p = 0; p < 12; p++) {
      const int slot = p * 8 + h;
      const ushort4 tiv = *(const ushort4*)(&ti[q][slot][0]);
      const f32x4 wv = *(const f32x4*)(&tw[q][slot][0]);
#pragma unroll
      for (int k = 0; k < 4; k++) {
        const unsigned pix =
            (k == 0) ? tiv.x : (k == 1) ? tiv.y : (k == 2) ? tiv.z : tiv.w;
        const float wgt = wv[k];
        const uint4 u = *(const uint4*)(vb + ((pix << 6) + laneoff));
        a0 += wgt * __uint_as_float(u.x << 16);
        a1 += wgt * __uint_as_float(u.x & 0xffff0000u);
        a2 += wgt * __uint_as_float(u.y << 16);
        a3 += wgt * __uint_as_float(u.y & 0xffff0000u);
        a4 += wgt * __uint_as_float(u.z << 16);
        a5 += wgt * __uint_as_float(u.z & 0xffff0000u);
        a6 += wgt * __uint_as_float(u.w << 16);
        a7 += wgt * __uint_as_float(u.w & 0xffff0000u);
      }
    }
    if (qv) {
      uint4 o;
      o.x = (unsigned)f2bf(a0) | ((unsigned)f2bf(a1) << 16);
      o.y = (unsigned)f2bf(a2) | ((unsigned)f2bf(a3) << 16);
      o.z = (unsigned)f2bf(a4) | ((unsigned)f2bf(a5) << 16);
      o.w = (unsigned)f2bf(a6) | ((unsigned)f2bf(a7) << 16);
      *(uint4*)(sampled + (size_t)bq * 256 + h * 32 + cg * 8) = o;
    }
  }
}

// ---------------- host launch ----------------
extern "C" void kernel_launch(void* const* d_in, const int* in_sizes, int n_in,
                              void* d_out, int out_size, void* d_ws, size_t ws_size,
                              hipStream_t stream) {
  const float* query      = (const float*)d_in[0];
  const float* refp       = (const float*)d_in[1];
  const float* value_flat = (const float*)d_in[2];
  const float* W_val      = (const float*)d_in[3];
  const float* b_val      = (const float*)d_in[4];
  const float* W_off      = (const float*)d_in[5];
  const float* b_off      = (const float*)d_in[6];
  const float* W_attn     = (const float*)d_in[7];
  const float* b_attn     = (const float*)d_in[8];
  const float* W_out      = (const float*)d_in[9];
  const float* b_out      = (const float*)d_in[10];

  char* w = (char*)d_ws;
  size_t o = 0;
  auto carve = [&](size_t bytes) -> void* {
    void* p = (void*)(w + o);
    o += (bytes + 255) & ~(size_t)255;
    return p;
  };
  unsigned short* Wval_t  = (unsigned short*)carve(256 * 256 * 2);
  unsigned short* Wcat_t  = (unsigned short*)carve(288 * 256 * 2);
  unsigned short* Wout_t  = (unsigned short*)carve(256 * 256 * 2);
  float*          bcat    = (float*)carve(288 * 4);
  unsigned short* value16 = (unsigned short*)carve((size_t)MTOT * 256 * 2);
  float*          logits  = (float*)carve((size_t)MTOT * 288 * 4);
  unsigned short* samp_bf = (unsigned short*)carve((size_t)MTOT * 256 * 2);

  prep_weights<<<288, 256, 0, stream>>>(W_val, W_off, W_attn, W_out, b_off, b_attn,
                                        Wval_t, Wcat_t, Wout_t, bcat);

  const int mg = (MTOT + 63) / 64;               // 348
  dim3 g12(mg, 2);
  gemm_fused12<<<g12, 256, 0, stream>>>(value_flat, query, Wval_t, Wcat_t,
                                        b_val, bcat, value16, logits);

  const int sgrid = (MTOT + 7) / 8;              // 2778
  msda_sample4<<<sgrid, 256, 0, stream>>>(value16, logits, refp, samp_bf);

  gemm_a16<<<mg, 256, 0, stream>>>(samp_bf, Wout_t, b_out, (float*)d_out);
}

// Round 8
// 189.710 us; speedup vs baseline: 1.5827x; 1.1177x over previous
//
#include <hip/hip_runtime.h>

// MSDeformAttn: B=2, LQ=LV=11109, D=256, NH=8, HD=32, NL=3, NP=4
// shapes: (92,92),(46,46),(23,23); starts: 0, 8464, 10580
#define LQn   11109
#define MTOT  22218   // B * LQ

typedef __attribute__((ext_vector_type(8))) short short8;
typedef __attribute__((ext_vector_type(4))) float f32x4;

__device__ __forceinline__ unsigned short f2bf(float f) {
  union { float f; unsigned int u; } v; v.f = f;
  unsigned int r = v.u + 0x7fffu + ((v.u >> 16) & 1u);  // RNE
  return (unsigned short)(r >> 16);
}

// bijective XCD chunk swizzle: consecutive logical blocks -> same XCD
__device__ __forceinline__ int xcd_swz(int bid, int nwg) {
  const int xcd = bid & 7, pos = bid >> 3;
  const int q = nwg >> 3, r = nwg & 7;
  return (xcd < r ? xcd * (q + 1) : r * (q + 1) + (xcd - r) * q) + pos;
}

// ---------------- weight prep: transpose to (N x K) bf16, concat biases ----------------
__global__ __launch_bounds__(256) void prep_weights(
    const float* __restrict__ Wval, const float* __restrict__ Woff,
    const float* __restrict__ Wattn, const float* __restrict__ Wout,
    const float* __restrict__ boff, const float* __restrict__ battn,
    unsigned short* __restrict__ Wval_t, unsigned short* __restrict__ Wcat_t,
    unsigned short* __restrict__ Wout_t, float* __restrict__ bcat) {
  int i = blockIdx.x * 256 + threadIdx.x;   // grid = 288 blocks -> i < 73728
  int n = i >> 8, k = i & 255;              // Wt[n][k] = W[k][n]
  if (n < 256) {
    Wval_t[i] = f2bf(Wval[k * 256 + n]);
    Wout_t[i] = f2bf(Wout[k * 256 + n]);
  }
  float src = (n < 192) ? Woff[k * 192 + n] : Wattn[k * 96 + (n - 192)];
  Wcat_t[i] = f2bf(src);
  if (i < 288) bcat[i] = (i < 192) ? boff[i] : battn[i - 192];
}

// ---------------- fused GEMM1+GEMM2, baseline 64x64 structure (10KB LDS,
// 8 blocks/CU) + 1-deep register prefetch: loads for kb+1 issue AFTER the
// second barrier of kb, overlapping ds_read+MFMA instead of stalling at
// vmcnt(0) each iteration. grid = (348, 9).
__global__ __launch_bounds__(256) void gemm_fused12(
    const float* __restrict__ Aval,           // (M,256) fp32
    const float* __restrict__ Aq,             // (M,256) fp32
    const unsigned short* __restrict__ Bval,  // (256,256) bf16 N-major
    const unsigned short* __restrict__ Bcat,  // (288,256) bf16 N-major
    const float* __restrict__ bval, const float* __restrict__ bcat,
    unsigned short* __restrict__ value16,     // [b][h][pix][32] bf16
    float* __restrict__ logits) {             // (M,288) fp32
  __shared__ unsigned short As[64][40];
  __shared__ unsigned short Bs[64][40];

  const int bm = blockIdx.x;
  int bn = blockIdx.y;
  const bool is2 = bn >= 4;
  if (is2) bn -= 4;
  const float* __restrict__ A = is2 ? Aq : Aval;
  const unsigned short* __restrict__ Bt = is2 ? Bcat : Bval;
  const float* __restrict__ bias = is2 ? bcat : bval;
  const int N = is2 ? 288 : 256;

  const int t = threadIdx.x;
  const int wave = t >> 6, lane = t & 63;
  const int wm = wave >> 1, wn = wave & 1;
  const int quad = lane >> 4, l16 = lane & 15;

  const int ldr = t >> 2;
  const int ldk = (t & 3) * 8;
  const int arow = bm * 64 + ldr;
  const int brow = bn * 64 + ldr;
  const bool aok = arow < MTOT;
  const bool bok = brow < N;
  const float* ap = A + (size_t)arow * 256 + ldk;
  const unsigned short* bp = Bt + (size_t)brow * 256 + ldk;

  f32x4 acc[2][2];
  for (int i = 0; i < 2; i++)
    for (int j = 0; j < 2; j++) acc[i][j] = (f32x4){0.f, 0.f, 0.f, 0.f};

  // prologue: load kb=0
  float4 a0 = {0.f, 0.f, 0.f, 0.f}, a1 = a0;
  uint4 bv = {0u, 0u, 0u, 0u};
  if (aok) { a0 = *(const float4*)(ap); a1 = *(const float4*)(ap + 4); }
  if (bok) bv = *(const uint4*)(bp);

  for (int kb = 0; kb < 8; kb++) {
    ushort4 lo, hi;
    lo.x = f2bf(a0.x); lo.y = f2bf(a0.y); lo.z = f2bf(a0.z); lo.w = f2bf(a0.w);
    hi.x = f2bf(a1.x); hi.y = f2bf(a1.y); hi.z = f2bf(a1.z); hi.w = f2bf(a1.w);
    __syncthreads();
    *(ushort4*)(&As[ldr][ldk]) = lo;
    *(ushort4*)(&As[ldr][ldk + 4]) = hi;
    *(uint4*)(&Bs[ldr][ldk]) = bv;
    __syncthreads();
    if (kb < 7) {                       // prefetch kb+1: overlaps compute below
      const int k1 = (kb + 1) * 32;
      if (aok) { a0 = *(const float4*)(ap + k1); a1 = *(const float4*)(ap + k1 + 4); }
      if (bok) bv = *(const uint4*)(bp + k1);
    }
    short8 af[2], bfr[2];
    for (int i = 0; i < 2; i++)
      af[i] = *(const short8*)(&As[wm * 32 + i * 16 + l16][quad * 8]);
    for (int j = 0; j < 2; j++)
      bfr[j] = *(const short8*)(&Bs[wn * 32 + j * 16 + l16][quad * 8]);
    for (int i = 0; i < 2; i++)
      for (int j = 0; j < 2; j++)
        acc[i][j] = __builtin_amdgcn_mfma_f32_16x16x32_bf16(af[i], bfr[j], acc[i][j], 0, 0, 0);
  }

  for (int i = 0; i < 2; i++)
    for (int j = 0; j < 2; j++) {
      int colg = bn * 64 + wn * 32 + j * 16 + l16;
      if (colg >= N) continue;
      float bsv = bias[colg];
      int row0 = bm * 64 + wm * 32 + i * 16 + quad * 4;
      for (int r = 0; r < 4; r++) {
        int rg = row0 + r;
        if (rg >= MTOT) continue;
        float v = acc[i][j][r] + bsv;
        if (is2) {
          logits[(size_t)rg * 288 + colg] = v;
        } else {
          int b = (rg >= LQn) ? 1 : 0;
          int p = rg - b * LQn;
          value16[((size_t)(b * 8 + (colg >> 5)) * LQn + p) * 32 + (colg & 31)] = f2bf(v);
        }
      }
    }
}

// ---------------- GEMM3: baseline structure + 1-deep register prefetch ----------------
// grid = (348, 4)
__global__ __launch_bounds__(256) void gemm_a16(
    const unsigned short* __restrict__ A,   // (M,256) bf16
    const unsigned short* __restrict__ Bt,  // (256,256) bf16 N-major
    const float* __restrict__ bias,
    float* __restrict__ C) {                // (M,256) fp32
  __shared__ unsigned short As[64][40];
  __shared__ unsigned short Bs[64][40];

  const int t = threadIdx.x;
  const int bm = blockIdx.x, bn = blockIdx.y;
  const int wave = t >> 6, lane = t & 63;
  const int wm = wave >> 1, wn = wave & 1;
  const int quad = lane >> 4, l16 = lane & 15;

  const int ldr = t >> 2;
  const int ldk = (t & 3) * 8;
  const int arow = bm * 64 + ldr;
  const int brow = bn * 64 + ldr;
  const bool aok = arow < MTOT;
  const unsigned short* ap = A + (size_t)arow * 256 + ldk;
  const unsigned short* bp = Bt + (size_t)brow * 256 + ldk;

  f32x4 acc[2][2];
  for (int i = 0; i < 2; i++)
    for (int j = 0; j < 2; j++) acc[i][j] = (f32x4){0.f, 0.f, 0.f, 0.f};

  uint4 av = {0u, 0u, 0u, 0u};
  uint4 bv;
  if (aok) av = *(const uint4*)(ap);
  bv = *(const uint4*)(bp);

  for (int kb = 0; kb < 8; kb++) {
    __syncthreads();
    *(uint4*)(&As[ldr][ldk]) = av;
    *(uint4*)(&Bs[ldr][ldk]) = bv;
    __syncthreads();
    if (kb < 7) {                       // prefetch kb+1
      const int k1 = (kb + 1) * 32;
      if (aok) av = *(const uint4*)(ap + k1);
      bv = *(const uint4*)(bp + k1);
    }
    short8 af[2], bfr[2];
    for (int i = 0; i < 2; i++)
      af[i] = *(const short8*)(&As[wm * 32 + i * 16 + l16][quad * 8]);
    for (int j = 0; j < 2; j++)
      bfr[j] = *(const short8*)(&Bs[wn * 32 + j * 16 + l16][quad * 8]);
    for (int i = 0; i < 2; i++)
      for (int j = 0; j < 2; j++)
        acc[i][j] = __builtin_amdgcn_mfma_f32_16x16x32_bf16(af[i], bfr[j], acc[i][j], 0, 0, 0);
  }

  for (int i = 0; i < 2; i++)
    for (int j = 0; j < 2; j++) {
      int colg = bn * 64 + wn * 32 + j * 16 + l16;
      float bsv = bias[colg];
      int row0 = bm * 64 + wm * 32 + i * 16 + quad * 4;
      for (int r = 0; r < 4; r++) {
        int rg = row0 + r;
        if (rg < MTOT) C[(size_t)rg * 256 + colg] = acc[i][j][r] + bsv;
      }
    }
}

// ---------------- sampling + softmax + weighted sum, v4 + XCD swizzle ----------------
// (proven 43-44 us; VGPR 40, occupancy ~47%)
__global__ __launch_bounds__(256) void msda_sample4(
    const unsigned short* __restrict__ value16,  // [b][h][pix][32] bf16
    const float* __restrict__ logits,            // (M,288)
    const float* __restrict__ refp,              // (M,3,2) (y,x)
    unsigned short* __restrict__ sampled) {      // (M,256) bf16
  __shared__ float          tw[8][96][4];   // 12.3 KB
  __shared__ unsigned short ti[8][96][4];   // 6.1 KB
  __shared__ float hmx[8][8], hrd[8][8];
  __shared__ float rfs[8][6];

  const int t = threadIdx.x;
  const int nbid = xcd_swz(blockIdx.x, gridDim.x);
  const int qbase = nbid * 8;

  if (t < 48) {
    int q = t / 6;
    if (qbase + q < MTOT) rfs[q][t - q * 6] = refp[(size_t)qbase * 6 + t];
  }
  if (t >= 64 && t < 128) {
    int tt = t - 64;
    int q = tt >> 3, h = tt & 7;
    int bq = qbase + q;
    if (bq < MTOT) {
      const float* lrow = logits + (size_t)bq * 288 + 192 + h * 12;
      float mx = -1e30f;
#pragma unroll
      for (int i = 0; i < 12; i++) mx = fmaxf(mx, lrow[i]);
      float den = 0.f;
#pragma unroll
      for (int i = 0; i < 12; i++) den += __expf(lrow[i] - mx);
      hmx[q][h] = mx;
      hrd[q][h] = 1.0f / den;
    }
  }
  __syncthreads();

  {
    const int Hs[3] = {92, 46, 23};
    const int Ss[3] = {0, 8464, 10580};
#pragma unroll
    for (int r = 0; r < 3; r++) {
      const int task = t + r * 256;
      const int q = task / 96, s = task - q * 96;
      const int bq = qbase + q;
      if (bq < MTOT) {
        const int h = s / 12, pl = s - h * 12;
        const int l = pl >> 2;
        const int H = Hs[l], W = Hs[l], S = Ss[l];
        const float* lrow = logits + (size_t)bq * 288;
        const float aw = __expf(lrow[192 + s] - hmx[q][h]) * hrd[q][h];
        const float offy = lrow[2 * s], offx = lrow[2 * s + 1];
        const float x = rfs[q][l * 2 + 1] * W + offx - 0.5f;
        const float y = rfs[q][l * 2 + 0] * H + offy - 0.5f;
        const float xf = floorf(x), yf = floorf(y);
        const int x0 = (int)xf, y0 = (int)yf;
        const float lx = x - xf, ly = y - yf;
        const bool xv0 = (x0 >= 0) & (x0 < W), xv1 = (x0 + 1 >= 0) & (x0 + 1 < W);
        const bool yv0 = (y0 >= 0) & (y0 < H), yv1 = (y0 + 1 >= 0) & (y0 + 1 < H);
        const int xc0 = min(max(x0, 0), W - 1), xc1 = min(max(x0 + 1, 0), W - 1);
        const int yc0 = min(max(y0, 0), H - 1), yc1 = min(max(y0 + 1, 0), H - 1);
        const int slot = pl * 8 + h;
        ti[q][slot][0] = (unsigned short)(S + yc0 * W + xc0);
        ti[q][slot][1] = (unsigned short)(S + yc0 * W + xc1);
        ti[q][slot][2] = (unsigned short)(S + yc1 * W + xc0);
        ti[q][slot][3] = (unsigned short)(S + yc1 * W + xc1);
        tw[q][slot][0] = (yv0 & xv0) ? aw * (1.f - ly) * (1.f - lx) : 0.f;
        tw[q][slot][1] = (yv0 & xv1) ? aw * (1.f - ly) * lx : 0.f;
        tw[q][slot][2] = (yv1 & xv0) ? aw * ly * (1.f - lx) : 0.f;
        tw[q][slot][3] = (yv1 & xv1) ? aw * ly * lx : 0.f;
      }
    }
  }
  __syncthreads();

  {
    const int w = t >> 6, lane = t & 63;
    const int q = w * 2 + (lane >> 5);
    const int h = (lane >> 2) & 7, cg = lane & 3;
    const int bq = qbase + q;
    const bool qv = bq < MTOT;
    const int bqc = qv ? bq : 0;
    const char* __restrict__ vb =
        (const char*)value16 + (size_t)(bqc / LQn) * ((size_t)LQn * 512);
    const unsigned laneoff = (unsigned)h * (LQn * 64u) + (unsigned)cg * 16u;

    float a0 = 0.f, a1 = 0.f, a2 = 0.f, a3 = 0.f;
    float a4 = 0.f, a5 = 0.f, a6 = 0.f, a7 = 0.f;
#pragma unroll
    for (int p = 0; p < 12; p++) {
      const int slot = p * 8 + h;
      const ushort4 tiv = *(const ushort4*)(&ti[q][slot][0]);
      const f32x4 wv = *(const f32x4*)(&tw[q][slot][0]);
#pragma unroll
      for (int k = 0; k < 4; k++) {
        const unsigned pix =
            (k == 0) ? tiv.x : (k == 1) ? tiv.y : (k == 2) ? tiv.z : tiv.w;
        const float wgt = wv[k];
        const uint4 u = *(const uint4*)(vb + ((pix << 6) + laneoff));
        a0 += wgt * __uint_as_float(u.x << 16);
        a1 += wgt * __uint_as_float(u.x & 0xffff0000u);
        a2 += wgt * __uint_as_float(u.y << 16);
        a3 += wgt * __uint_as_float(u.y & 0xffff0000u);
        a4 += wgt * __uint_as_float(u.z << 16);
        a5 += wgt * __uint_as_float(u.z & 0xffff0000u);
        a6 += wgt * __uint_as_float(u.w << 16);
        a7 += wgt * __uint_as_float(u.w & 0xffff0000u);
      }
    }
    if (qv) {
      uint4 o;
      o.x = (unsigned)f2bf(a0) | ((unsigned)f2bf(a1) << 16);
      o.y = (unsigned)f2bf(a2) | ((unsigned)f2bf(a3) << 16);
      o.z = (unsigned)f2bf(a4) | ((unsigned)f2bf(a5) << 16);
      o.w = (unsigned)f2bf(a6) | ((unsigned)f2bf(a7) << 16);
      *(uint4*)(sampled + (size_t)bq * 256 + h * 32 + cg * 8) = o;
    }
  }
}

// ---------------- host launch ----------------
extern "C" void kernel_launch(void* const* d_in, const int* in_sizes, int n_in,
                              void* d_out, int out_size, void* d_ws, size_t ws_size,
                              hipStream_t stream) {
  const float* query      = (const float*)d_in[0];
  const float* refp       = (const float*)d_in[1];
  const float* value_flat = (const float*)d_in[2];
  const float* W_val      = (const float*)d_in[3];
  const float* b_val      = (const float*)d_in[4];
  const float* W_off      = (const float*)d_in[5];
  const float* b_off      = (const float*)d_in[6];
  const float* W_attn     = (const float*)d_in[7];
  const float* b_attn     = (const float*)d_in[8];
  const float* W_out      = (const float*)d_in[9];
  const float* b_out      = (const float*)d_in[10];

  char* w = (char*)d_ws;
  size_t o = 0;
  auto carve = [&](size_t bytes) -> void* {
    void* p = (void*)(w + o);
    o += (bytes + 255) & ~(size_t)255;
    return p;
  };
  unsigned short* Wval_t  = (unsigned short*)carve(256 * 256 * 2);
  unsigned short* Wcat_t  = (unsigned short*)carve(288 * 256 * 2);
  unsigned short* Wout_t  = (unsigned short*)carve(256 * 256 * 2);
  float*          bcat    = (float*)carve(288 * 4);
  unsigned short* value16 = (unsigned short*)carve((size_t)MTOT * 256 * 2);
  float*          logits  = (float*)carve((size_t)MTOT * 288 * 4);
  unsigned short* samp_bf = (unsigned short*)carve((size_t)MTOT * 256 * 2);

  prep_weights<<<288, 256, 0, stream>>>(W_val, W_off, W_attn, W_out, b_off, b_attn,
                                        Wval_t, Wcat_t, Wout_t, bcat);

  const int mg = (MTOT + 63) / 64;               // 348
  dim3 g12(mg, 9);                               // 4 value-proj tiles + 5 logits tiles
  gemm_fused12<<<g12, 256, 0, stream>>>(value_flat, query, Wval_t, Wcat_t,
                                        b_val, bcat, value16, logits);

  const int sgrid = (MTOT + 7) / 8;              // 2778
  msda_sample4<<<sgrid, 256, 0, stream>>>(value16, logits, refp, samp_bf);

  dim3 g3(mg, 4);
  gemm_a16<<<g3, 256, 0, stream>>>(samp_bf, Wout_t, b_out, (float*)d_out);
}